// Round 21
// baseline (260.463 us; speedup 1.0000x reference)
//
#include <hip/hip_runtime.h>

#define G 64
#define N 2048
#define E 32768
#define GN (G*N)   // 131072
#define PADR 36    // shorts per LDS row (72 B, 8B-aligned for b64)

typedef __attribute__((ext_vector_type(8))) short bf16x8;
typedef __attribute__((ext_vector_type(4))) float f32x4;

__device__ __forceinline__ float4 ld4(const float* p) { return *reinterpret_cast<const float4*>(p); }
__device__ __forceinline__ unsigned short f2bf(float x) {   // RNE
    unsigned u = __float_as_uint(x);
    u += 0x7FFF + ((u >> 16) & 1);
    return (unsigned short)(u >> 16);
}
__device__ __forceinline__ unsigned pack2(float a, float b) {
    return (unsigned)f2bf(a) | ((unsigned)f2bf(b) << 16);
}
__device__ __forceinline__ float bflo(unsigned u) { return __uint_as_float(u << 16); }
__device__ __forceinline__ float bfhi(unsigned u) { return __uint_as_float(u & 0xFFFF0000u); }
__device__ __forceinline__ float bfs(short s) { return __uint_as_float(((unsigned)(unsigned short)s) << 16); }

// bijective XCD swizzle (grid % 8 == 0)
__device__ __forceinline__ int swz(int bid, int chunk) { return (bid & 7) * chunk + (bid >> 3); }

// ---------------- init: 0..63 degree count + desc-degree sort + JDS level offsets;
//                   64..103 weight prep; 104 tgt zero ----------------
__global__ __launch_bounds__(1024) void k_init(const int* __restrict__ ei,
        float* __restrict__ dinv, int* __restrict__ perm, int* __restrict__ rankg,
        int* __restrict__ sdeg, float* __restrict__ sdinv, int* __restrict__ lvlG,
        const float* __restrict__ wres, const float* __restrict__ gw,
        const float* __restrict__ wfc, unsigned short* __restrict__ Wt,
        float* __restrict__ tgt) {
    int t = threadIdx.x;
    if (blockIdx.x == G + 40) {
        #pragma unroll
        for (int j = 0; j < 8; ++j) tgt[j*1024 + t] = 0.f;
        return;
    }
    if (blockIdx.x >= G) {
        if (t >= 256) return;
        int pb = blockIdx.x - G;           // 0..39
        int m = pb >> 3;
        int tid = (pb & 7) * 256 + t;      // 0..2047
        const float* src = (m == 0) ? wres : (m < 4 ? gw + (size_t)(m-1)*16384 : wfc);
        int c = tid >> 4, q = tid & 15;
        float v[8];
        #pragma unroll
        for (int j = 0; j < 8; ++j) v[j] = src[(q*8 + j)*128 + c];
        uint4 p;
        p.x = pack2(v[0], v[1]); p.y = pack2(v[2], v[3]);
        p.z = pack2(v[4], v[5]); p.w = pack2(v[6], v[7]);
        *reinterpret_cast<uint4*>(Wt + (size_t)m*16384 + c*128 + ((q ^ (c & 7)) << 3)) = p;
        return;
    }
    // ---- degree count + descending-degree counting sort + JDS levels ----
    int g = blockIdx.x;
    __shared__ int scnt[2048];
    __shared__ int hist[128];
    __shared__ int basev[129];
    __shared__ int lvl[128];
    __shared__ int ctr[128];
    scnt[t] = 0; scnt[t + 1024] = 0;
    if (t < 128) { hist[t] = 0; ctr[t] = 0; }
    __syncthreads();
    const int* dstp = ei + (size_t)g*2*E + E;
    for (int e = t; e < E; e += 1024) atomicAdd(&scnt[dstp[e]], 1);
    __syncthreads();
    int a = scnt[2*t], b = scnt[2*t + 1];
    dinv[(g<<11) + 2*t]     = rsqrtf((float)(a + 1));
    dinv[(g<<11) + 2*t + 1] = rsqrtf((float)(b + 1));
    int ba = min(a, 127), bb = min(b, 127);
    atomicAdd(&hist[ba], 1);
    atomicAdd(&hist[bb], 1);
    __syncthreads();
    if (t == 0) {
        int suf = 0;
        basev[128] = 0;
        for (int d = 127; d >= 0; --d) { suf += hist[d]; basev[d] = suf; }
        int run = 0;
        for (int i = 0; i < 128; ++i) { lvl[i] = run; run += basev[i + 1]; }
    }
    __syncthreads();
    {
        int sa = basev[ba + 1] + atomicAdd(&ctr[ba], 1);
        perm[(g<<11) + sa] = 2*t;
        sdeg[(g<<11) + sa] = a;
        sdinv[(g<<11) + sa] = rsqrtf((float)(a + 1));
        rankg[(g<<11) + 2*t] = sa;
        int sb = basev[bb + 1] + atomicAdd(&ctr[bb], 1);
        perm[(g<<11) + sb] = 2*t + 1;
        sdeg[(g<<11) + sb] = b;
        sdinv[(g<<11) + sb] = rsqrtf((float)(b + 1));
        rankg[(g<<11) + 2*t + 1] = sb;
    }
    if (t < 128) lvlG[g*128 + t] = lvl[t];
}

// ---------------- residual gather-GEMM (blocks G..) + JDS fill (blocks 0..63) ----------------
// X1 = relu(X0 @ W0 + bres)   (single accumulator set now)
__global__ __launch_bounds__(512) void k_gemm_g2(const int* __restrict__ fidx,
        const float* __restrict__ tab, const unsigned short* __restrict__ Wt,
        const float* __restrict__ bres,
        unsigned short* __restrict__ X1,
        const int* __restrict__ ei, const int* __restrict__ rankg,
        const int* __restrict__ lvlG, int* __restrict__ padj) {
    __shared__ unsigned short sW[16384];   // 32 KB (fill blocks alias as cur/rank/lvl)
    const int t = threadIdx.x;

    if (blockIdx.x < G) {
        int* cur   = reinterpret_cast<int*>(sW);
        int* rankL = cur + 2048;
        int* lvlL  = rankL + 2048;   // 2048+2048+128 ints = 16.5KB < 32KB ok
        int g = blockIdx.x;
        #pragma unroll
        for (int i = 0; i < 4; ++i) {
            cur[i*512 + t] = 0;
            rankL[i*512 + t] = rankg[(g<<11) + i*512 + t];
        }
        if (t < 128) lvlL[t] = lvlG[g*128 + t];
        __syncthreads();
        const int* srcp = ei + (size_t)g*2*E;
        const int* dstp = srcp + E;
        for (int e = t; e < E; e += 512) {
            int dst = dstp[e];
            int i = atomicAdd(&cur[dst], 1);
            padj[(size_t)g*E + lvlL[i] + rankL[dst]] = srcp[e];
        }
        return;
    }

    {
        const float4* s = reinterpret_cast<const float4*>(Wt);
        float4* d = reinterpret_cast<float4*>(sW);
        #pragma unroll
        for (int i = 0; i < 4; ++i) d[i*512 + t] = s[i*512 + t];
    }
    __syncthreads();

    const int lane = t & 63, w = t >> 6;
    const int wrow = (w & 3) << 6;
    const int wcol = (w >> 2) << 6;
    const size_t row0 = (size_t)swz(blockIdx.x - G, GN/256/8) * 256;
    const int l15 = lane & 15, l4 = lane >> 4;

    size_t rbase[4];
    const float* rowp[4];
    #pragma unroll
    for (int f2 = 0; f2 < 4; ++f2) {
        rbase[f2] = row0 + wrow + f2*16 + l15;
        rowp[f2] = tab + (size_t)fidx[rbase[f2]] * 128;
    }

    f32x4 acc0[4][4];
    #pragma unroll
    for (int i = 0; i < 4; ++i)
        #pragma unroll
        for (int j = 0; j < 4; ++j) acc0[i][j] = (f32x4){0.f, 0.f, 0.f, 0.f};

    #pragma unroll
    for (int kk = 0; kk < 4; ++kk) {
        bf16x8 xf[4];
        #pragma unroll
        for (int f2 = 0; f2 < 4; ++f2) {
            int col = (kk << 5) + (l4 << 3);
            float4 u = ld4(rowp[f2] + col);
            float4 v = ld4(rowp[f2] + col + 4);
            bf16x8 r;
            r[0] = (short)f2bf(u.x); r[1] = (short)f2bf(u.y);
            r[2] = (short)f2bf(u.z); r[3] = (short)f2bf(u.w);
            r[4] = (short)f2bf(v.x); r[5] = (short)f2bf(v.y);
            r[6] = (short)f2bf(v.z); r[7] = (short)f2bf(v.w);
            xf[f2] = r;
        }
        #pragma unroll
        for (int f = 0; f < 4; ++f) {
            int c = wcol + f*16 + l15;
            int off = c*128 + (((kk*4 + l4) ^ (c & 7)) << 3);
            bf16x8 wf0 = *reinterpret_cast<const bf16x8*>(&sW[off]);
            #pragma unroll
            for (int f2 = 0; f2 < 4; ++f2)
                acc0[f2][f] = __builtin_amdgcn_mfma_f32_16x16x32_bf16(wf0, xf[f2], acc0[f2][f], 0, 0, 0);
        }
    }

    #pragma unroll
    for (int f = 0; f < 4; ++f) {
        int colb = wcol + f*16 + (l4 << 2);
        float4 bs = ld4(bres + colb);
        #pragma unroll
        for (int f2 = 0; f2 < 4; ++f2) {
            f32x4 v0 = acc0[f2][f];
            uint2 p0;
            p0.x = pack2(fmaxf(v0[0] + bs.x, 0.f), fmaxf(v0[1] + bs.y, 0.f));
            p0.y = pack2(fmaxf(v0[2] + bs.z, 0.f), fmaxf(v0[3] + bs.w, 0.f));
            *reinterpret_cast<uint2*>(X1 + (rbase[f2] << 7) + colb) = p0;
        }
    }
}

// ---------------- MFMA GEMM (fc1 + fused mean) ----------------
__global__ __launch_bounds__(512) void k_gemm2(const unsigned short* __restrict__ A,
        const unsigned short* __restrict__ A2, const unsigned short* __restrict__ Wt,
        const float* __restrict__ bias, float* __restrict__ tgt) {
    __shared__ unsigned short sW[16384];
    const int t = threadIdx.x;
    {
        const float4* s = reinterpret_cast<const float4*>(Wt);
        float4* d = reinterpret_cast<float4*>(sW);
        #pragma unroll
        for (int i = 0; i < 4; ++i) d[i*512 + t] = s[i*512 + t];
    }
    __syncthreads();

    const int lane = t & 63, w = t >> 6;
    const int wrow = (w & 3) << 6;
    const int wcol = (w >> 2) << 6;
    const size_t row0 = (size_t)swz(blockIdx.x, GN/256/8) * 256;
    const int l15 = lane & 15, l4 = lane >> 4;

    size_t rbase[4];
    #pragma unroll
    for (int f2 = 0; f2 < 4; ++f2) rbase[f2] = row0 + wrow + f2*16 + l15;

    f32x4 acc[4][4];
    #pragma unroll
    for (int i = 0; i < 4; ++i)
        #pragma unroll
        for (int j = 0; j < 4; ++j) acc[i][j] = (f32x4){0.f, 0.f, 0.f, 0.f};

    #pragma unroll
    for (int kk = 0; kk < 4; ++kk) {
        bf16x8 xf[4];
        #pragma unroll
        for (int f2 = 0; f2 < 4; ++f2) {
            const unsigned short* ap = A + (rbase[f2] << 7) + (kk << 5) + (l4 << 3);
            bf16x8 x = *reinterpret_cast<const bf16x8*>(ap);
            bf16x8 y = *reinterpret_cast<const bf16x8*>(A2 + (rbase[f2] << 7) + (kk << 5) + (l4 << 3));
            bf16x8 r;
            #pragma unroll
            for (int j = 0; j < 8; ++j) r[j] = (short)f2bf(bfs(x[j]) + bfs(y[j]));
            xf[f2] = r;
        }
        #pragma unroll
        for (int f = 0; f < 4; ++f) {
            int c = wcol + f*16 + l15;
            int off = c*128 + (((kk*4 + l4) ^ (c & 7)) << 3);
            bf16x8 wf = *reinterpret_cast<const bf16x8*>(&sW[off]);
            #pragma unroll
            for (int f2 = 0; f2 < 4; ++f2)
                acc[f2][f] = __builtin_amdgcn_mfma_f32_16x16x32_bf16(wf, xf[f2], acc[f2][f], 0, 0, 0);
        }
    }

    float cs[4][4];
    #pragma unroll
    for (int f = 0; f < 4; ++f) {
        int colb = wcol + f*16 + (l4 << 2);
        float4 bs = ld4(bias + colb);
        #pragma unroll
        for (int j = 0; j < 4; ++j) cs[f][j] = 0.f;
        #pragma unroll
        for (int f2 = 0; f2 < 4; ++f2) {
            cs[f][0] += fmaxf(acc[f2][f][0] + bs.x, 0.f);
            cs[f][1] += fmaxf(acc[f2][f][1] + bs.y, 0.f);
            cs[f][2] += fmaxf(acc[f2][f][2] + bs.z, 0.f);
            cs[f][3] += fmaxf(acc[f2][f][3] + bs.w, 0.f);
        }
    }
    #pragma unroll
    for (int d = 1; d < 16; d <<= 1)
        #pragma unroll
        for (int f = 0; f < 4; ++f)
            #pragma unroll
            for (int j = 0; j < 4; ++j)
                cs[f][j] += __shfl_xor(cs[f][j], d);
    if (l15 == 0) {
        int g = (int)(row0 >> 11);
        #pragma unroll
        for (int f = 0; f < 4; ++f)
            #pragma unroll
            for (int j = 0; j < 4; ++j)
                atomicAdd(&tgt[g*128 + wcol + f*16 + (l4 << 2) + j], cs[f][j]);
    }
}

// ---------------- fused layer: MFMA h'-slice into LDS, then JDS aggregation ----------------
// GATHER=1: X rows come from tab[fidx[row]] (fp32->bf16), layer 0.
// GATHER=0: X rows from bf16 Xin.
// block = (graph, 32-col slice), XCD-swizzled so a graph's 4 slices share one XCD L2.
template<int GATHER>
__global__ __launch_bounds__(1024) void k_fused(const unsigned short* __restrict__ Xin,
        const int* __restrict__ fidx, const float* __restrict__ tab,
        const unsigned short* __restrict__ WtL,
        const int* __restrict__ padj, const int* __restrict__ lvlG,
        const int* __restrict__ perm, const int* __restrict__ sdeg,
        const float* __restrict__ sdinv, const float* __restrict__ dinv,
        const float* __restrict__ bias,
        unsigned short* __restrict__ Xout) {
    __shared__ unsigned short sIN[2048 * PADR];   // 144 KiB
    __shared__ int lvlL[128];
    const int t = threadIdx.x;
    const int wg = swz(blockIdx.x, 32);           // same-graph slices -> same XCD
    const int g  = wg >> 2;
    const int c0 = (wg & 3) << 5;

    if (t < 128) lvlL[t] = lvlG[g*128 + t];

    const int lane = t & 63, wv = t >> 6;
    const int l15 = lane & 15, l4 = lane >> 4;

    // W fragments (A-operand) for this block's 32 cols
    bf16x8 wf[2][4];
    #pragma unroll
    for (int f = 0; f < 2; ++f) {
        int c = c0 + f*16 + l15;
        #pragma unroll
        for (int kk = 0; kk < 4; ++kk)
            wf[f][kk] = *reinterpret_cast<const bf16x8*>(&WtL[c*128 + (((kk*4 + l4) ^ (c & 7)) << 3)]);
    }

    // Phase 1: compute h' slice. Wave wv owns row-tiles 8wv..8wv+7 (16 rows each).
    const unsigned short* xg = (GATHER ? nullptr : Xin + (((size_t)g << 11) << 7));
    #pragma unroll
    for (int rt = 0; rt < 8; ++rt) {
        int row = (((wv << 3) + rt) << 4) + l15;
        f32x4 acc0 = (f32x4){0.f,0.f,0.f,0.f};
        f32x4 acc1 = (f32x4){0.f,0.f,0.f,0.f};
        const float* gp;
        if (GATHER) gp = tab + (size_t)fidx[(g << 11) + row] * 128;
        #pragma unroll
        for (int kk = 0; kk < 4; ++kk) {
            bf16x8 xf;
            if (GATHER) {
                int col = (kk << 5) + (l4 << 3);
                float4 u = ld4(gp + col);
                float4 v = ld4(gp + col + 4);
                xf[0] = (short)f2bf(u.x); xf[1] = (short)f2bf(u.y);
                xf[2] = (short)f2bf(u.z); xf[3] = (short)f2bf(u.w);
                xf[4] = (short)f2bf(v.x); xf[5] = (short)f2bf(v.y);
                xf[6] = (short)f2bf(v.z); xf[7] = (short)f2bf(v.w);
            } else {
                xf = *reinterpret_cast<const bf16x8*>(xg + ((size_t)row << 7) + (kk << 5) + (l4 << 3));
            }
            acc0 = __builtin_amdgcn_mfma_f32_16x16x32_bf16(wf[0][kk], xf, acc0, 0, 0, 0);
            acc1 = __builtin_amdgcn_mfma_f32_16x16x32_bf16(wf[1][kk], xf, acc1, 0, 0, 0);
        }
        float d = dinv[(g << 11) + row];
        uint2 p0, p1;
        p0.x = pack2(acc0[0]*d, acc0[1]*d); p0.y = pack2(acc0[2]*d, acc0[3]*d);
        p1.x = pack2(acc1[0]*d, acc1[1]*d); p1.y = pack2(acc1[2]*d, acc1[3]*d);
        *reinterpret_cast<uint2*>(&sIN[row*PADR + (l4 << 2)])      = p0;
        *reinterpret_cast<uint2*>(&sIN[row*PADR + 16 + (l4 << 2)]) = p1;
    }
    __syncthreads();

    // Phase 2: JDS aggregation
    const int* pa = padj + (size_t)g*E;
    float bs[32];
    #pragma unroll
    for (int q = 0; q < 8; ++q) {
        float4 b4 = ld4(bias + c0 + q*4);
        bs[q*4] = b4.x; bs[q*4+1] = b4.y; bs[q*4+2] = b4.z; bs[q*4+3] = b4.w;
    }

    #pragma unroll
    for (int half = 0; half < 2; ++half) {
        const int r = t + (half << 10);
        const int n  = perm[(g << 11) + r];
        const int dg = sdeg[(g << 11) + r];
        const float dv = sdinv[(g << 11) + r];
        float acc[32];
        {
            const unsigned short* rp = &sIN[n*PADR];
            #pragma unroll
            for (int q = 0; q < 8; ++q) {
                uint2 u = *reinterpret_cast<const uint2*>(rp + q*4);
                acc[q*4]   = bflo(u.x); acc[q*4+1] = bfhi(u.x);
                acc[q*4+2] = bflo(u.y); acc[q*4+3] = bfhi(u.y);
            }
        }
        int i = 0;
        for (; i + 2 <= dg; i += 2) {
            int s0 = pa[lvlL[i] + r];
            int s1 = pa[lvlL[i+1] + r];
            const unsigned short* rp0 = &sIN[s0*PADR];
            const unsigned short* rp1 = &sIN[s1*PADR];
            uint2 u0[8], u1[8];
            #pragma unroll
            for (int q = 0; q < 8; ++q) u0[q] = *reinterpret_cast<const uint2*>(rp0 + q*4);
            #pragma unroll
            for (int q = 0; q < 8; ++q) u1[q] = *reinterpret_cast<const uint2*>(rp1 + q*4);
            #pragma unroll
            for (int q = 0; q < 8; ++q) {
                acc[q*4]   += bflo(u0[q].x) + bflo(u1[q].x);
                acc[q*4+1] += bfhi(u0[q].x) + bfhi(u1[q].x);
                acc[q*4+2] += bflo(u0[q].y) + bflo(u1[q].y);
                acc[q*4+3] += bfhi(u0[q].y) + bfhi(u1[q].y);
            }
        }
        if (i < dg) {
            int s = pa[lvlL[i] + r];
            const unsigned short* rp = &sIN[s*PADR];
            #pragma unroll
            for (int q = 0; q < 8; ++q) {
                uint2 u = *reinterpret_cast<const uint2*>(rp + q*4);
                acc[q*4]   += bflo(u.x); acc[q*4+1] += bfhi(u.x);
                acc[q*4+2] += bflo(u.y); acc[q*4+3] += bfhi(u.y);
            }
        }
        unsigned short* op = Xout + (((size_t)(g << 11) + n) << 7) + c0;
        uint4 o0, o1;
        o0.x = pack2(fmaxf(acc[0]*dv+bs[0],0.f),  fmaxf(acc[1]*dv+bs[1],0.f));
        o0.y = pack2(fmaxf(acc[2]*dv+bs[2],0.f),  fmaxf(acc[3]*dv+bs[3],0.f));
        o0.z = pack2(fmaxf(acc[4]*dv+bs[4],0.f),  fmaxf(acc[5]*dv+bs[5],0.f));
        o0.w = pack2(fmaxf(acc[6]*dv+bs[6],0.f),  fmaxf(acc[7]*dv+bs[7],0.f));
        o1.x = pack2(fmaxf(acc[8]*dv+bs[8],0.f),  fmaxf(acc[9]*dv+bs[9],0.f));
        o1.y = pack2(fmaxf(acc[10]*dv+bs[10],0.f),fmaxf(acc[11]*dv+bs[11],0.f));
        o1.z = pack2(fmaxf(acc[12]*dv+bs[12],0.f),fmaxf(acc[13]*dv+bs[13],0.f));
        o1.w = pack2(fmaxf(acc[14]*dv+bs[14],0.f),fmaxf(acc[15]*dv+bs[15],0.f));
        *reinterpret_cast<uint4*>(op) = o0;
        *reinterpret_cast<uint4*>(op + 8) = o1;
        uint4 o2, o3;
        o2.x = pack2(fmaxf(acc[16]*dv+bs[16],0.f),fmaxf(acc[17]*dv+bs[17],0.f));
        o2.y = pack2(fmaxf(acc[18]*dv+bs[18],0.f),fmaxf(acc[19]*dv+bs[19],0.f));
        o2.z = pack2(fmaxf(acc[20]*dv+bs[20],0.f),fmaxf(acc[21]*dv+bs[21],0.f));
        o2.w = pack2(fmaxf(acc[22]*dv+bs[22],0.f),fmaxf(acc[23]*dv+bs[23],0.f));
        o3.x = pack2(fmaxf(acc[24]*dv+bs[24],0.f),fmaxf(acc[25]*dv+bs[25],0.f));
        o3.y = pack2(fmaxf(acc[26]*dv+bs[26],0.f),fmaxf(acc[27]*dv+bs[27],0.f));
        o3.z = pack2(fmaxf(acc[28]*dv+bs[28],0.f),fmaxf(acc[29]*dv+bs[29],0.f));
        o3.w = pack2(fmaxf(acc[30]*dv+bs[30],0.f),fmaxf(acc[31]*dv+bs[31],0.f));
        *reinterpret_cast<uint4*>(op + 16) = o2;
        *reinterpret_cast<uint4*>(op + 24) = o3;
    }
}

// ---------------- logits + log_softmax: one wave per graph ----------------
__global__ __launch_bounds__(64) void k_final(const float* __restrict__ tgt,
        const float* __restrict__ lw, const float* __restrict__ lb, float* __restrict__ outp) {
    int g = blockIdx.x, lane = threadIdx.x;
    float l0 = 0.f, l1 = 0.f;
    #pragma unroll
    for (int c = lane; c < 128; c += 64) {
        float v = tgt[g*128 + c] * (1.0f/2048.0f);
        l0 += v * lw[c*2];
        l1 += v * lw[c*2 + 1];
    }
    #pragma unroll
    for (int d = 32; d; d >>= 1) { l0 += __shfl_xor(l0, d); l1 += __shfl_xor(l1, d); }
    if (lane == 0) {
        l0 += lb[0]; l1 += lb[1];
        float m = fmaxf(l0, l1);
        float lse = m + logf(expf(l0 - m) + expf(l1 - m));
        outp[g*2]         = l0 - lse;
        outp[g*2 + 1]     = l1 - lse;
        outp[G*2 + g*2]     = l0;
        outp[G*2 + g*2 + 1] = l1;
    }
}

extern "C" void kernel_launch(void* const* d_in, const int* in_sizes, int n_in,
                              void* d_out, int out_size, void* d_ws, size_t ws_size,
                              hipStream_t stream) {
    const float* all_features = (const float*)d_in[0];
    const int*   fidx = (const int*)d_in[1];
    const int*   ei   = (const int*)d_in[2];
    // d_in[3] = action (always 2 -> 3 GCN layers)
    const float* wres = (const float*)d_in[4];
    const float* bres = (const float*)d_in[5];
    const float* gw   = (const float*)d_in[6];
    const float* gb   = (const float*)d_in[7];
    const float* wfc  = (const float*)d_in[8];
    const float* bfc  = (const float*)d_in[9];
    const float* lw   = (const float*)d_in[10];
    const float* lb   = (const float*)d_in[11];
    float* out = (float*)d_out;

    char* ws = (char*)d_ws;
    size_t o = 0;
    auto alloc = [&](size_t bytes) { char* p = ws + o; o += (bytes + 255) & ~(size_t)255; return p; };
    unsigned short* X  = (unsigned short*)alloc((size_t)GN*128*2);   // layer outputs (ping)
    unsigned short* Xb = (unsigned short*)alloc((size_t)GN*128*2);   // pong
    unsigned short* X1 = (unsigned short*)alloc((size_t)GN*128*2);   // residual
    unsigned short* Wt = (unsigned short*)alloc((size_t)5*16384*2);
    int*   padj  = (int*)alloc((size_t)G*E*4);
    int*   lvlG  = (int*)alloc((size_t)G*128*4);
    int*   perm  = (int*)alloc((size_t)GN*4);
    int*   rankg = (int*)alloc((size_t)GN*4);
    int*   sdeg  = (int*)alloc((size_t)GN*4);
    float* sdinv = (float*)alloc((size_t)GN*4);
    float* dinv  = (float*)alloc((size_t)GN*4);
    float* tgt   = (float*)alloc((size_t)G*128*4);

    // degree count + sort + JDS levels + weight prep + tgt zero
    k_init<<<G + 41, 1024, 0, stream>>>(ei, dinv, perm, rankg, sdeg, sdinv, lvlG,
                                        wres, gw, wfc, Wt, tgt);

    // residual gather-GEMM (X1 only) with JDS fill overlapped
    k_gemm_g2<<<G + GN/256, 512, 0, stream>>>(fidx, all_features, Wt, bres, X1,
                                              ei, rankg, lvlG, padj);

    // layer 0: fused gather-GEMM h'-slice + aggregation
    k_fused<1><<<G*4, 1024, 0, stream>>>(nullptr, fidx, all_features, Wt + (size_t)16384,
                                         padj, lvlG, perm, sdeg, sdinv, dinv, gb, X);
    // layers 1,2: fused MFMA h'-slice + aggregation
    k_fused<0><<<G*4, 1024, 0, stream>>>(X, nullptr, nullptr, Wt + (size_t)2*16384,
                                         padj, lvlG, perm, sdeg, sdinv, dinv, gb + 128, Xb);
    k_fused<0><<<G*4, 1024, 0, stream>>>(Xb, nullptr, nullptr, Wt + (size_t)3*16384,
                                         padj, lvlG, perm, sdeg, sdinv, dinv, gb + 256, X);

    // fc1 + mean fused
    k_gemm2<<<GN/256, 512, 0, stream>>>(X, X1, Wt + (size_t)4*16384, bfc, tgt);

    k_final<<<G, 64, 0, stream>>>(tgt, lw, lb, out);
}

// Round 22
// 242.364 us; speedup vs baseline: 1.0747x; 1.0747x over previous
//
#include <hip/hip_runtime.h>

#define G 64
#define N 2048
#define E 32768
#define GN (G*N)   // 131072
#define PADR 36    // shorts per LDS row (72 B, 8B-aligned for b64)

typedef __attribute__((ext_vector_type(8))) short bf16x8;
typedef __attribute__((ext_vector_type(4))) float f32x4;

__device__ __forceinline__ float4 ld4(const float* p) { return *reinterpret_cast<const float4*>(p); }
__device__ __forceinline__ unsigned short f2bf(float x) {   // RNE
    unsigned u = __float_as_uint(x);
    u += 0x7FFF + ((u >> 16) & 1);
    return (unsigned short)(u >> 16);
}
__device__ __forceinline__ unsigned pack2(float a, float b) {
    return (unsigned)f2bf(a) | ((unsigned)f2bf(b) << 16);
}
__device__ __forceinline__ float bflo(unsigned u) { return __uint_as_float(u << 16); }
__device__ __forceinline__ float bfhi(unsigned u) { return __uint_as_float(u & 0xFFFF0000u); }
__device__ __forceinline__ float bfs(short s) { return __uint_as_float(((unsigned)(unsigned short)s) << 16); }

// bijective XCD swizzle (grid % 8 == 0)
__device__ __forceinline__ int swz(int bid, int chunk) { return (bid & 7) * chunk + (bid >> 3); }

// ---------------- init: 0..63 degree count + desc-degree sort + JDS level offsets;
//                   64..103 weight prep; 104 tgt zero ----------------
__global__ __launch_bounds__(1024) void k_init(const int* __restrict__ ei,
        float* __restrict__ dinv, int* __restrict__ perm, int* __restrict__ rankg,
        int* __restrict__ sdeg, float* __restrict__ sdinv, int* __restrict__ lvlG,
        const float* __restrict__ wres, const float* __restrict__ gw,
        const float* __restrict__ wfc, unsigned short* __restrict__ Wt,
        float* __restrict__ tgt) {
    int t = threadIdx.x;
    if (blockIdx.x == G + 40) {
        #pragma unroll
        for (int j = 0; j < 8; ++j) tgt[j*1024 + t] = 0.f;
        return;
    }
    if (blockIdx.x >= G) {
        if (t >= 256) return;
        int pb = blockIdx.x - G;           // 0..39
        int m = pb >> 3;
        int tid = (pb & 7) * 256 + t;      // 0..2047
        const float* src = (m == 0) ? wres : (m < 4 ? gw + (size_t)(m-1)*16384 : wfc);
        int c = tid >> 4, q = tid & 15;
        float v[8];
        #pragma unroll
        for (int j = 0; j < 8; ++j) v[j] = src[(q*8 + j)*128 + c];
        uint4 p;
        p.x = pack2(v[0], v[1]); p.y = pack2(v[2], v[3]);
        p.z = pack2(v[4], v[5]); p.w = pack2(v[6], v[7]);
        *reinterpret_cast<uint4*>(Wt + (size_t)m*16384 + c*128 + ((q ^ (c & 7)) << 3)) = p;
        return;
    }
    // ---- degree count + descending-degree counting sort + JDS levels ----
    int g = blockIdx.x;
    __shared__ int scnt[2048];
    __shared__ int hist[128];
    __shared__ int basev[129];
    __shared__ int lvl[128];
    __shared__ int ctr[128];
    scnt[t] = 0; scnt[t + 1024] = 0;
    if (t < 128) { hist[t] = 0; ctr[t] = 0; }
    __syncthreads();
    const int* dstp = ei + (size_t)g*2*E + E;
    for (int e = t; e < E; e += 1024) atomicAdd(&scnt[dstp[e]], 1);
    __syncthreads();
    int a = scnt[2*t], b = scnt[2*t + 1];
    dinv[(g<<11) + 2*t]     = rsqrtf((float)(a + 1));
    dinv[(g<<11) + 2*t + 1] = rsqrtf((float)(b + 1));
    int ba = min(a, 127), bb = min(b, 127);
    atomicAdd(&hist[ba], 1);
    atomicAdd(&hist[bb], 1);
    __syncthreads();
    if (t == 0) {
        int suf = 0;
        basev[128] = 0;
        for (int d = 127; d >= 0; --d) { suf += hist[d]; basev[d] = suf; }
        int run = 0;
        for (int i = 0; i < 128; ++i) { lvl[i] = run; run += basev[i + 1]; }
    }
    __syncthreads();
    {
        int sa = basev[ba + 1] + atomicAdd(&ctr[ba], 1);
        perm[(g<<11) + sa] = 2*t;
        sdeg[(g<<11) + sa] = a;
        sdinv[(g<<11) + sa] = rsqrtf((float)(a + 1));
        rankg[(g<<11) + 2*t] = sa;
        int sb = basev[bb + 1] + atomicAdd(&ctr[bb], 1);
        perm[(g<<11) + sb] = 2*t + 1;
        sdeg[(g<<11) + sb] = b;
        sdinv[(g<<11) + sb] = rsqrtf((float)(b + 1));
        rankg[(g<<11) + 2*t + 1] = sb;
    }
    if (t < 128) lvlG[g*128 + t] = lvl[t];
}

// ---------------- twin gather-GEMM (blocks G..G+511) + JDS fill (blocks 0..63) ----------------
// X1 = relu(X0 @ W0 + bres);  Hb = (X0 @ W1) * dinv[row]
__global__ __launch_bounds__(512) void k_gemm_g2(const int* __restrict__ fidx,
        const float* __restrict__ tab, const unsigned short* __restrict__ Wt,
        const float* __restrict__ bres, const float* __restrict__ dinv,
        unsigned short* __restrict__ X1, unsigned short* __restrict__ Hb,
        const int* __restrict__ ei, const int* __restrict__ rankg,
        const int* __restrict__ lvlG, int* __restrict__ padj) {
    __shared__ unsigned short sW[2*16384];   // 64 KB (fill blocks alias as cur/rank/lvl)
    const int t = threadIdx.x;

    if (blockIdx.x < G) {
        int* cur   = reinterpret_cast<int*>(sW);
        int* rankL = cur + 2048;
        int* lvlL  = rankL + 2048;
        int g = blockIdx.x;
        #pragma unroll
        for (int i = 0; i < 4; ++i) {
            cur[i*512 + t] = 0;
            rankL[i*512 + t] = rankg[(g<<11) + i*512 + t];
        }
        if (t < 128) lvlL[t] = lvlG[g*128 + t];
        __syncthreads();
        const int* srcp = ei + (size_t)g*2*E;
        const int* dstp = srcp + E;
        for (int e = t; e < E; e += 512) {
            int dst = dstp[e];
            int i = atomicAdd(&cur[dst], 1);
            padj[(size_t)g*E + lvlL[i] + rankL[dst]] = srcp[e];
        }
        return;
    }

    {
        const float4* s = reinterpret_cast<const float4*>(Wt);
        float4* d = reinterpret_cast<float4*>(sW);
        #pragma unroll
        for (int i = 0; i < 8; ++i) d[i*512 + t] = s[i*512 + t];
    }
    __syncthreads();

    const int lane = t & 63, w = t >> 6;
    const int wrow = (w & 3) << 6;
    const int wcol = (w >> 2) << 6;
    const size_t row0 = (size_t)swz(blockIdx.x - G, GN/256/8) * 256;
    const int l15 = lane & 15, l4 = lane >> 4;

    size_t rbase[4];
    const float* rowp[4];
    #pragma unroll
    for (int f2 = 0; f2 < 4; ++f2) {
        rbase[f2] = row0 + wrow + f2*16 + l15;
        rowp[f2] = tab + (size_t)fidx[rbase[f2]] * 128;
    }

    f32x4 acc0[4][4], acc1[4][4];
    #pragma unroll
    for (int i = 0; i < 4; ++i)
        #pragma unroll
        for (int j = 0; j < 4; ++j) {
            acc0[i][j] = (f32x4){0.f, 0.f, 0.f, 0.f};
            acc1[i][j] = (f32x4){0.f, 0.f, 0.f, 0.f};
        }

    #pragma unroll
    for (int kk = 0; kk < 4; ++kk) {
        bf16x8 xf[4];
        #pragma unroll
        for (int f2 = 0; f2 < 4; ++f2) {
            int col = (kk << 5) + (l4 << 3);
            float4 u = ld4(rowp[f2] + col);
            float4 v = ld4(rowp[f2] + col + 4);
            bf16x8 r;
            r[0] = (short)f2bf(u.x); r[1] = (short)f2bf(u.y);
            r[2] = (short)f2bf(u.z); r[3] = (short)f2bf(u.w);
            r[4] = (short)f2bf(v.x); r[5] = (short)f2bf(v.y);
            r[6] = (short)f2bf(v.z); r[7] = (short)f2bf(v.w);
            xf[f2] = r;
        }
        #pragma unroll
        for (int f = 0; f < 4; ++f) {
            int c = wcol + f*16 + l15;
            int off = c*128 + (((kk*4 + l4) ^ (c & 7)) << 3);
            bf16x8 wf0 = *reinterpret_cast<const bf16x8*>(&sW[off]);
            bf16x8 wf1 = *reinterpret_cast<const bf16x8*>(&sW[16384 + off]);
            #pragma unroll
            for (int f2 = 0; f2 < 4; ++f2) {
                acc0[f2][f] = __builtin_amdgcn_mfma_f32_16x16x32_bf16(wf0, xf[f2], acc0[f2][f], 0, 0, 0);
                acc1[f2][f] = __builtin_amdgcn_mfma_f32_16x16x32_bf16(wf1, xf[f2], acc1[f2][f], 0, 0, 0);
            }
        }
    }

    float dv[4];
    #pragma unroll
    for (int f2 = 0; f2 < 4; ++f2) dv[f2] = dinv[rbase[f2]];

    #pragma unroll
    for (int f = 0; f < 4; ++f) {
        int colb = wcol + f*16 + (l4 << 2);
        float4 bs = ld4(bres + colb);
        #pragma unroll
        for (int f2 = 0; f2 < 4; ++f2) {
            f32x4 v0 = acc0[f2][f];
            uint2 p0;
            p0.x = pack2(fmaxf(v0[0] + bs.x, 0.f), fmaxf(v0[1] + bs.y, 0.f));
            p0.y = pack2(fmaxf(v0[2] + bs.z, 0.f), fmaxf(v0[3] + bs.w, 0.f));
            *reinterpret_cast<uint2*>(X1 + (rbase[f2] << 7) + colb) = p0;
            f32x4 v1 = acc1[f2][f];
            float d = dv[f2];
            uint2 p1;
            p1.x = pack2(v1[0]*d, v1[1]*d);
            p1.y = pack2(v1[2]*d, v1[3]*d);
            *reinterpret_cast<uint2*>(Hb + (rbase[f2] << 7) + colb) = p1;
        }
    }
}

// ---------------- MFMA GEMM (fc1 + fused mean) ----------------
__global__ __launch_bounds__(512) void k_gemm2(const unsigned short* __restrict__ A,
        const unsigned short* __restrict__ A2, const unsigned short* __restrict__ Wt,
        const float* __restrict__ bias, float* __restrict__ tgt) {
    __shared__ unsigned short sW[16384];
    const int t = threadIdx.x;
    {
        const float4* s = reinterpret_cast<const float4*>(Wt);
        float4* d = reinterpret_cast<float4*>(sW);
        #pragma unroll
        for (int i = 0; i < 4; ++i) d[i*512 + t] = s[i*512 + t];
    }
    __syncthreads();

    const int lane = t & 63, w = t >> 6;
    const int wrow = (w & 3) << 6;
    const int wcol = (w >> 2) << 6;
    const size_t row0 = (size_t)swz(blockIdx.x, GN/256/8) * 256;
    const int l15 = lane & 15, l4 = lane >> 4;

    size_t rbase[4];
    #pragma unroll
    for (int f2 = 0; f2 < 4; ++f2) rbase[f2] = row0 + wrow + f2*16 + l15;

    f32x4 acc[4][4];
    #pragma unroll
    for (int i = 0; i < 4; ++i)
        #pragma unroll
        for (int j = 0; j < 4; ++j) acc[i][j] = (f32x4){0.f, 0.f, 0.f, 0.f};

    #pragma unroll
    for (int kk = 0; kk < 4; ++kk) {
        bf16x8 xf[4];
        #pragma unroll
        for (int f2 = 0; f2 < 4; ++f2) {
            const unsigned short* ap = A + (rbase[f2] << 7) + (kk << 5) + (l4 << 3);
            bf16x8 x = *reinterpret_cast<const bf16x8*>(ap);
            bf16x8 y = *reinterpret_cast<const bf16x8*>(A2 + (rbase[f2] << 7) + (kk << 5) + (l4 << 3));
            bf16x8 r;
            #pragma unroll
            for (int j = 0; j < 8; ++j) r[j] = (short)f2bf(bfs(x[j]) + bfs(y[j]));
            xf[f2] = r;
        }
        #pragma unroll
        for (int f = 0; f < 4; ++f) {
            int c = wcol + f*16 + l15;
            int off = c*128 + (((kk*4 + l4) ^ (c & 7)) << 3);
            bf16x8 wf = *reinterpret_cast<const bf16x8*>(&sW[off]);
            #pragma unroll
            for (int f2 = 0; f2 < 4; ++f2)
                acc[f2][f] = __builtin_amdgcn_mfma_f32_16x16x32_bf16(wf, xf[f2], acc[f2][f], 0, 0, 0);
        }
    }

    float cs[4][4];
    #pragma unroll
    for (int f = 0; f < 4; ++f) {
        int colb = wcol + f*16 + (l4 << 2);
        float4 bs = ld4(bias + colb);
        #pragma unroll
        for (int j = 0; j < 4; ++j) cs[f][j] = 0.f;
        #pragma unroll
        for (int f2 = 0; f2 < 4; ++f2) {
            cs[f][0] += fmaxf(acc[f2][f][0] + bs.x, 0.f);
            cs[f][1] += fmaxf(acc[f2][f][1] + bs.y, 0.f);
            cs[f][2] += fmaxf(acc[f2][f][2] + bs.z, 0.f);
            cs[f][3] += fmaxf(acc[f2][f][3] + bs.w, 0.f);
        }
    }
    #pragma unroll
    for (int d = 1; d < 16; d <<= 1)
        #pragma unroll
        for (int f = 0; f < 4; ++f)
            #pragma unroll
            for (int j = 0; j < 4; ++j)
                cs[f][j] += __shfl_xor(cs[f][j], d);
    if (l15 == 0) {
        int g = (int)(row0 >> 11);
        #pragma unroll
        for (int f = 0; f < 4; ++f)
            #pragma unroll
            for (int j = 0; j < 4; ++j)
                atomicAdd(&tgt[g*128 + wcol + f*16 + (l4 << 2) + j], cs[f][j]);
    }
}

// ---------------- layer-0 aggregation: stage h' slice from global + JDS edges ----------------
__global__ __launch_bounds__(1024) void k_agg(const unsigned short* __restrict__ h,
        const int* __restrict__ padj, const int* __restrict__ lvlG,
        const int* __restrict__ perm, const int* __restrict__ sdeg,
        const float* __restrict__ sdinv, const float* __restrict__ bias,
        unsigned short* __restrict__ out) {
    __shared__ unsigned short sIN[2048 * PADR];   // 144 KiB
    __shared__ int lvlL[128];
    const int t = threadIdx.x;
    const int g  = blockIdx.x >> 2;
    const int c0 = (blockIdx.x & 3) << 5;
    const unsigned short* hg = h + (((size_t)g << 11) << 7) + c0;

    if (t < 128) lvlL[t] = lvlG[g*128 + t];
    {
        int r0 = t >> 3;
        int j  = t & 7;
        for (int i = 0; i < 16; ++i) {
            int r = r0 + (i << 7);
            uint2 v = *reinterpret_cast<const uint2*>(hg + ((size_t)r << 7) + j*4);
            *reinterpret_cast<uint2*>(&sIN[r*PADR + j*4]) = v;
        }
    }
    __syncthreads();

    const int* pa = padj + (size_t)g*E;
    float bs[32];
    #pragma unroll
    for (int q = 0; q < 8; ++q) {
        float4 b4 = ld4(bias + c0 + q*4);
        bs[q*4] = b4.x; bs[q*4+1] = b4.y; bs[q*4+2] = b4.z; bs[q*4+3] = b4.w;
    }

    #pragma unroll
    for (int half = 0; half < 2; ++half) {
        const int r = t + (half << 10);
        const int n  = perm[(g << 11) + r];
        const int dg = sdeg[(g << 11) + r];
        const float dv = sdinv[(g << 11) + r];
        float acc[32];
        {
            const unsigned short* rp = &sIN[n*PADR];
            #pragma unroll
            for (int q = 0; q < 8; ++q) {
                uint2 u = *reinterpret_cast<const uint2*>(rp + q*4);
                acc[q*4]   = bflo(u.x); acc[q*4+1] = bfhi(u.x);
                acc[q*4+2] = bflo(u.y); acc[q*4+3] = bfhi(u.y);
            }
        }
        int i = 0;
        for (; i + 2 <= dg; i += 2) {
            int s0 = pa[lvlL[i] + r];
            int s1 = pa[lvlL[i+1] + r];
            const unsigned short* rp0 = &sIN[s0*PADR];
            const unsigned short* rp1 = &sIN[s1*PADR];
            uint2 u0[8], u1[8];
            #pragma unroll
            for (int q = 0; q < 8; ++q) u0[q] = *reinterpret_cast<const uint2*>(rp0 + q*4);
            #pragma unroll
            for (int q = 0; q < 8; ++q) u1[q] = *reinterpret_cast<const uint2*>(rp1 + q*4);
            #pragma unroll
            for (int q = 0; q < 8; ++q) {
                acc[q*4]   += bflo(u0[q].x) + bflo(u1[q].x);
                acc[q*4+1] += bfhi(u0[q].x) + bfhi(u1[q].x);
                acc[q*4+2] += bflo(u0[q].y) + bflo(u1[q].y);
                acc[q*4+3] += bfhi(u0[q].y) + bfhi(u1[q].y);
            }
        }
        if (i < dg) {
            int s = pa[lvlL[i] + r];
            const unsigned short* rp = &sIN[s*PADR];
            #pragma unroll
            for (int q = 0; q < 8; ++q) {
                uint2 u = *reinterpret_cast<const uint2*>(rp + q*4);
                acc[q*4]   += bflo(u.x); acc[q*4+1] += bfhi(u.x);
                acc[q*4+2] += bflo(u.y); acc[q*4+3] += bfhi(u.y);
            }
        }
        unsigned short* op = out + (((size_t)(g << 11) + n) << 7) + c0;
        uint4 o0, o1;
        o0.x = pack2(fmaxf(acc[0]*dv+bs[0],0.f),  fmaxf(acc[1]*dv+bs[1],0.f));
        o0.y = pack2(fmaxf(acc[2]*dv+bs[2],0.f),  fmaxf(acc[3]*dv+bs[3],0.f));
        o0.z = pack2(fmaxf(acc[4]*dv+bs[4],0.f),  fmaxf(acc[5]*dv+bs[5],0.f));
        o0.w = pack2(fmaxf(acc[6]*dv+bs[6],0.f),  fmaxf(acc[7]*dv+bs[7],0.f));
        o1.x = pack2(fmaxf(acc[8]*dv+bs[8],0.f),  fmaxf(acc[9]*dv+bs[9],0.f));
        o1.y = pack2(fmaxf(acc[10]*dv+bs[10],0.f),fmaxf(acc[11]*dv+bs[11],0.f));
        o1.z = pack2(fmaxf(acc[12]*dv+bs[12],0.f),fmaxf(acc[13]*dv+bs[13],0.f));
        o1.w = pack2(fmaxf(acc[14]*dv+bs[14],0.f),fmaxf(acc[15]*dv+bs[15],0.f));
        *reinterpret_cast<uint4*>(op) = o0;
        *reinterpret_cast<uint4*>(op + 8) = o1;
        uint4 o2, o3;
        o2.x = pack2(fmaxf(acc[16]*dv+bs[16],0.f),fmaxf(acc[17]*dv+bs[17],0.f));
        o2.y = pack2(fmaxf(acc[18]*dv+bs[18],0.f),fmaxf(acc[19]*dv+bs[19],0.f));
        o2.z = pack2(fmaxf(acc[20]*dv+bs[20],0.f),fmaxf(acc[21]*dv+bs[21],0.f));
        o2.w = pack2(fmaxf(acc[22]*dv+bs[22],0.f),fmaxf(acc[23]*dv+bs[23],0.f));
        o3.x = pack2(fmaxf(acc[24]*dv+bs[24],0.f),fmaxf(acc[25]*dv+bs[25],0.f));
        o3.y = pack2(fmaxf(acc[26]*dv+bs[26],0.f),fmaxf(acc[27]*dv+bs[27],0.f));
        o3.z = pack2(fmaxf(acc[28]*dv+bs[28],0.f),fmaxf(acc[29]*dv+bs[29],0.f));
        o3.w = pack2(fmaxf(acc[30]*dv+bs[30],0.f),fmaxf(acc[31]*dv+bs[31],0.f));
        *reinterpret_cast<uint4*>(op + 16) = o2;
        *reinterpret_cast<uint4*>(op + 24) = o3;
    }
}

// ---------------- fused layer (1,2): MFMA h'-slice into LDS, then JDS aggregation ----------------
__global__ __launch_bounds__(1024) void k_fused(const unsigned short* __restrict__ Xin,
        const unsigned short* __restrict__ WtL,
        const int* __restrict__ padj, const int* __restrict__ lvlG,
        const int* __restrict__ perm, const int* __restrict__ sdeg,
        const float* __restrict__ sdinv, const float* __restrict__ dinv,
        const float* __restrict__ bias,
        unsigned short* __restrict__ Xout) {
    __shared__ unsigned short sIN[2048 * PADR];   // 144 KiB
    __shared__ int lvlL[128];
    const int t = threadIdx.x;
    const int wg = swz(blockIdx.x, 32);           // same-graph slices -> same XCD
    const int g  = wg >> 2;
    const int c0 = (wg & 3) << 5;

    if (t < 128) lvlL[t] = lvlG[g*128 + t];

    const int lane = t & 63, wv = t >> 6;
    const int l15 = lane & 15, l4 = lane >> 4;

    bf16x8 wf[2][4];
    #pragma unroll
    for (int f = 0; f < 2; ++f) {
        int c = c0 + f*16 + l15;
        #pragma unroll
        for (int kk = 0; kk < 4; ++kk)
            wf[f][kk] = *reinterpret_cast<const bf16x8*>(&WtL[c*128 + (((kk*4 + l4) ^ (c & 7)) << 3)]);
    }

    const unsigned short* xg = Xin + (((size_t)g << 11) << 7);
    #pragma unroll
    for (int rt = 0; rt < 8; ++rt) {
        int row = (((wv << 3) + rt) << 4) + l15;
        f32x4 acc0 = (f32x4){0.f,0.f,0.f,0.f};
        f32x4 acc1 = (f32x4){0.f,0.f,0.f,0.f};
        #pragma unroll
        for (int kk = 0; kk < 4; ++kk) {
            bf16x8 xf = *reinterpret_cast<const bf16x8*>(xg + ((size_t)row << 7) + (kk << 5) + (l4 << 3));
            acc0 = __builtin_amdgcn_mfma_f32_16x16x32_bf16(wf[0][kk], xf, acc0, 0, 0, 0);
            acc1 = __builtin_amdgcn_mfma_f32_16x16x32_bf16(wf[1][kk], xf, acc1, 0, 0, 0);
        }
        float d = dinv[(g << 11) + row];
        uint2 p0, p1;
        p0.x = pack2(acc0[0]*d, acc0[1]*d); p0.y = pack2(acc0[2]*d, acc0[3]*d);
        p1.x = pack2(acc1[0]*d, acc1[1]*d); p1.y = pack2(acc1[2]*d, acc1[3]*d);
        *reinterpret_cast<uint2*>(&sIN[row*PADR + (l4 << 2)])      = p0;
        *reinterpret_cast<uint2*>(&sIN[row*PADR + 16 + (l4 << 2)]) = p1;
    }
    __syncthreads();

    const int* pa = padj + (size_t)g*E;
    float bs[32];
    #pragma unroll
    for (int q = 0; q < 8; ++q) {
        float4 b4 = ld4(bias + c0 + q*4);
        bs[q*4] = b4.x; bs[q*4+1] = b4.y; bs[q*4+2] = b4.z; bs[q*4+3] = b4.w;
    }

    #pragma unroll
    for (int half = 0; half < 2; ++half) {
        const int r = t + (half << 10);
        const int n  = perm[(g << 11) + r];
        const int dg = sdeg[(g << 11) + r];
        const float dv = sdinv[(g << 11) + r];
        float acc[32];
        {
            const unsigned short* rp = &sIN[n*PADR];
            #pragma unroll
            for (int q = 0; q < 8; ++q) {
                uint2 u = *reinterpret_cast<const uint2*>(rp + q*4);
                acc[q*4]   = bflo(u.x); acc[q*4+1] = bfhi(u.x);
                acc[q*4+2] = bflo(u.y); acc[q*4+3] = bfhi(u.y);
            }
        }
        int i = 0;
        for (; i + 2 <= dg; i += 2) {
            int s0 = pa[lvlL[i] + r];
            int s1 = pa[lvlL[i+1] + r];
            const unsigned short* rp0 = &sIN[s0*PADR];
            const unsigned short* rp1 = &sIN[s1*PADR];
            uint2 u0[8], u1[8];
            #pragma unroll
            for (int q = 0; q < 8; ++q) u0[q] = *reinterpret_cast<const uint2*>(rp0 + q*4);
            #pragma unroll
            for (int q = 0; q < 8; ++q) u1[q] = *reinterpret_cast<const uint2*>(rp1 + q*4);
            #pragma unroll
            for (int q = 0; q < 8; ++q) {
                acc[q*4]   += bflo(u0[q].x) + bflo(u1[q].x);
                acc[q*4+1] += bfhi(u0[q].x) + bfhi(u1[q].x);
                acc[q*4+2] += bflo(u0[q].y) + bflo(u1[q].y);
                acc[q*4+3] += bfhi(u0[q].y) + bfhi(u1[q].y);
            }
        }
        if (i < dg) {
            int s = pa[lvlL[i] + r];
            const unsigned short* rp = &sIN[s*PADR];
            #pragma unroll
            for (int q = 0; q < 8; ++q) {
                uint2 u = *reinterpret_cast<const uint2*>(rp + q*4);
                acc[q*4]   += bflo(u.x); acc[q*4+1] += bfhi(u.x);
                acc[q*4+2] += bflo(u.y); acc[q*4+3] += bfhi(u.y);
            }
        }
        unsigned short* op = Xout + (((size_t)(g << 11) + n) << 7) + c0;
        uint4 o0, o1;
        o0.x = pack2(fmaxf(acc[0]*dv+bs[0],0.f),  fmaxf(acc[1]*dv+bs[1],0.f));
        o0.y = pack2(fmaxf(acc[2]*dv+bs[2],0.f),  fmaxf(acc[3]*dv+bs[3],0.f));
        o0.z = pack2(fmaxf(acc[4]*dv+bs[4],0.f),  fmaxf(acc[5]*dv+bs[5],0.f));
        o0.w = pack2(fmaxf(acc[6]*dv+bs[6],0.f),  fmaxf(acc[7]*dv+bs[7],0.f));
        o1.x = pack2(fmaxf(acc[8]*dv+bs[8],0.f),  fmaxf(acc[9]*dv+bs[9],0.f));
        o1.y = pack2(fmaxf(acc[10]*dv+bs[10],0.f),fmaxf(acc[11]*dv+bs[11],0.f));
        o1.z = pack2(fmaxf(acc[12]*dv+bs[12],0.f),fmaxf(acc[13]*dv+bs[13],0.f));
        o1.w = pack2(fmaxf(acc[14]*dv+bs[14],0.f),fmaxf(acc[15]*dv+bs[15],0.f));
        *reinterpret_cast<uint4*>(op) = o0;
        *reinterpret_cast<uint4*>(op + 8) = o1;
        uint4 o2, o3;
        o2.x = pack2(fmaxf(acc[16]*dv+bs[16],0.f),fmaxf(acc[17]*dv+bs[17],0.f));
        o2.y = pack2(fmaxf(acc[18]*dv+bs[18],0.f),fmaxf(acc[19]*dv+bs[19],0.f));
        o2.z = pack2(fmaxf(acc[20]*dv+bs[20],0.f),fmaxf(acc[21]*dv+bs[21],0.f));
        o2.w = pack2(fmaxf(acc[22]*dv+bs[22],0.f),fmaxf(acc[23]*dv+bs[23],0.f));
        o3.x = pack2(fmaxf(acc[24]*dv+bs[24],0.f),fmaxf(acc[25]*dv+bs[25],0.f));
        o3.y = pack2(fmaxf(acc[26]*dv+bs[26],0.f),fmaxf(acc[27]*dv+bs[27],0.f));
        o3.z = pack2(fmaxf(acc[28]*dv+bs[28],0.f),fmaxf(acc[29]*dv+bs[29],0.f));
        o3.w = pack2(fmaxf(acc[30]*dv+bs[30],0.f),fmaxf(acc[31]*dv+bs[31],0.f));
        *reinterpret_cast<uint4*>(op + 16) = o2;
        *reinterpret_cast<uint4*>(op + 24) = o3;
    }
}

// ---------------- logits + log_softmax: one wave per graph ----------------
__global__ __launch_bounds__(64) void k_final(const float* __restrict__ tgt,
        const float* __restrict__ lw, const float* __restrict__ lb, float* __restrict__ outp) {
    int g = blockIdx.x, lane = threadIdx.x;
    float l0 = 0.f, l1 = 0.f;
    #pragma unroll
    for (int c = lane; c < 128; c += 64) {
        float v = tgt[g*128 + c] * (1.0f/2048.0f);
        l0 += v * lw[c*2];
        l1 += v * lw[c*2 + 1];
    }
    #pragma unroll
    for (int d = 32; d; d >>= 1) { l0 += __shfl_xor(l0, d); l1 += __shfl_xor(l1, d); }
    if (lane == 0) {
        l0 += lb[0]; l1 += lb[1];
        float m = fmaxf(l0, l1);
        float lse = m + logf(expf(l0 - m) + expf(l1 - m));
        outp[g*2]         = l0 - lse;
        outp[g*2 + 1]     = l1 - lse;
        outp[G*2 + g*2]     = l0;
        outp[G*2 + g*2 + 1] = l1;
    }
}

extern "C" void kernel_launch(void* const* d_in, const int* in_sizes, int n_in,
                              void* d_out, int out_size, void* d_ws, size_t ws_size,
                              hipStream_t stream) {
    const float* all_features = (const float*)d_in[0];
    const int*   fidx = (const int*)d_in[1];
    const int*   ei   = (const int*)d_in[2];
    // d_in[3] = action (always 2 -> 3 GCN layers)
    const float* wres = (const float*)d_in[4];
    const float* bres = (const float*)d_in[5];
    const float* gw   = (const float*)d_in[6];
    const float* gb   = (const float*)d_in[7];
    const float* wfc  = (const float*)d_in[8];
    const float* bfc  = (const float*)d_in[9];
    const float* lw   = (const float*)d_in[10];
    const float* lb   = (const float*)d_in[11];
    float* out = (float*)d_out;

    char* ws = (char*)d_ws;
    size_t o = 0;
    auto alloc = [&](size_t bytes) { char* p = ws + o; o += (bytes + 255) & ~(size_t)255; return p; };
    unsigned short* X  = (unsigned short*)alloc((size_t)GN*128*2);   // layer outputs (ping)
    unsigned short* Xb = (unsigned short*)alloc((size_t)GN*128*2);   // pong / layer-0 h'
    unsigned short* X1 = (unsigned short*)alloc((size_t)GN*128*2);   // residual
    unsigned short* Wt = (unsigned short*)alloc((size_t)5*16384*2);
    int*   padj  = (int*)alloc((size_t)G*E*4);
    int*   lvlG  = (int*)alloc((size_t)G*128*4);
    int*   perm  = (int*)alloc((size_t)GN*4);
    int*   rankg = (int*)alloc((size_t)GN*4);
    int*   sdeg  = (int*)alloc((size_t)GN*4);
    float* sdinv = (float*)alloc((size_t)GN*4);
    float* dinv  = (float*)alloc((size_t)GN*4);
    float* tgt   = (float*)alloc((size_t)G*128*4);

    // degree count + sort + JDS levels + weight prep + tgt zero
    k_init<<<G + 41, 1024, 0, stream>>>(ei, dinv, perm, rankg, sdeg, sdinv, lvlG,
                                        wres, gw, wfc, Wt, tgt);

    // twin gather-GEMM (X1, layer-0 h' into Xb) with JDS fill overlapped
    k_gemm_g2<<<G + GN/256, 512, 0, stream>>>(fidx, all_features, Wt, bres, dinv, X1, Xb,
                                              ei, rankg, lvlG, padj);

    // layer 0: aggregate h' (global) -> X
    k_agg<<<G*4, 1024, 0, stream>>>(Xb, padj, lvlG, perm, sdeg, sdinv, gb, X);
    // layers 1,2: fused MFMA h'-slice + aggregation
    k_fused<<<G*4, 1024, 0, stream>>>(X, Wt + (size_t)2*16384, padj, lvlG, perm, sdeg, sdinv,
                                      dinv, gb + 128, Xb);
    k_fused<<<G*4, 1024, 0, stream>>>(Xb, Wt + (size_t)3*16384, padj, lvlG, perm, sdeg, sdinv,
                                      dinv, gb + 256, X);

    // fc1 + mean fused
    k_gemm2<<<GN/256, 512, 0, stream>>>(X, X1, Wt + (size_t)4*16384, bfc, tgt);

    k_final<<<G, 64, 0, stream>>>(tgt, lw, lb, out);
}